// Round 6
// baseline (444.058 us; speedup 1.0000x reference)
//
#include <hip/hip_runtime.h>
#include <hip/hip_bf16.h>
#include <hip/hip_fp16.h>

#define N_NODES 200000
#define N_EDGES 500000
#define F_IN    165
#define HID     256
#define SX      192   // padded f16 row stride (24 half8 segs, 16B-aligned rows)
#define NB      782   // ceil(N_NODES/256) scan blocks

typedef float    floatx4 __attribute__((ext_vector_type(4)));
typedef float    floatx4a __attribute__((ext_vector_type(4), aligned(16)));
typedef float    float4u __attribute__((ext_vector_type(4), aligned(4)));
typedef _Float16 half8   __attribute__((ext_vector_type(8)));

// ---------- K0: x (f32, stride 165) -> xh (f16 half8 segs, stride 24) ----------
__global__ void cast_x_kernel(const float* __restrict__ x, half8* __restrict__ xh8) {
    int idx = blockIdx.x * blockDim.x + threadIdx.x;   // < N*24
    int row = idx / 24;
    int p = idx - row * 24;
    int f0 = p * 8;
    const float* px = x + (long)row * F_IN + f0;
    half8 r;
    if (f0 + 8 <= F_IN) {
        float4u lo = *(const float4u*)px;
        float4u hi = *(const float4u*)(px + 4);
#pragma unroll
        for (int q = 0; q < 4; ++q) r[q] = (_Float16)lo[q];
#pragma unroll
        for (int q = 0; q < 4; ++q) r[4 + q] = (_Float16)hi[q];
    } else {
#pragma unroll
        for (int q = 0; q < 8; ++q)
            r[q] = (f0 + q < F_IN) ? (_Float16)px[q] : (_Float16)0.0f;
    }
    xh8[idx] = r;
}

// ---------- K1: dst-degree histogram ----------
__global__ void hist_kernel(const int* __restrict__ ei, int* __restrict__ degi) {
    int e = blockIdx.x * blockDim.x + threadIdx.x;
    if (e < N_EDGES) atomicAdd(&degi[ei[N_EDGES + e]], 1);
}

// ---------- K2a: per-block degree sums ----------
__global__ __launch_bounds__(256) void block_sum_kernel(const int* __restrict__ degi,
                                                        int* __restrict__ bsum) {
    __shared__ int sh[256];
    int t = threadIdx.x, i = blockIdx.x * 256 + t;
    sh[t] = (i < N_NODES) ? degi[i] : 0;
    __syncthreads();
#pragma unroll
    for (int off = 128; off > 0; off >>= 1) {
        if (t < off) sh[t] += sh[t + off];
        __syncthreads();
    }
    if (t == 0) bsum[blockIdx.x] = sh[0];
}

// ---------- K2b: scan the 782 block sums (1 block) ----------
__global__ __launch_bounds__(1024) void scan_bsum_kernel(const int* __restrict__ bsum,
                                                         int* __restrict__ boff,
                                                         int* __restrict__ row_start) {
    __shared__ int sh[1024];
    int t = threadIdx.x;
    int v = (t < NB) ? bsum[t] : 0;
    sh[t] = v;
    __syncthreads();
    for (int off = 1; off < 1024; off <<= 1) {
        int u = (t >= off) ? sh[t - off] : 0;
        __syncthreads();
        sh[t] += u;
        __syncthreads();
    }
    if (t < NB) boff[t] = sh[t] - v;               // exclusive
    if (t == 1023) row_start[N_NODES] = sh[1023];  // total = E
}

// ---------- K2c: emit row_start / cursor / invdeg ----------
__global__ __launch_bounds__(256) void scan_emit_kernel(const int* __restrict__ degi,
                                                        const int* __restrict__ boff,
                                                        int* __restrict__ row_start,
                                                        int* __restrict__ cursor,
                                                        float* __restrict__ invdeg) {
    __shared__ int sh[256];
    int t = threadIdx.x, i = blockIdx.x * 256 + t;
    int d = (i < N_NODES) ? degi[i] : 0;
    sh[t] = d;
    __syncthreads();
#pragma unroll
    for (int off = 1; off < 256; off <<= 1) {
        int u = (t >= off) ? sh[t - off] : 0;
        __syncthreads();
        sh[t] += u;
        __syncthreads();
    }
    if (i < N_NODES) {
        int row = boff[blockIdx.x] + sh[t] - d;    // exclusive scan value
        row_start[i] = row;
        cursor[i] = row;
        invdeg[i] = 1.0f / fmaxf((float)d, 1.0f);
    }
}

// ---------- K3: bucket edges into CSR ----------
__global__ void scatter_edges_kernel(const int* __restrict__ ei,
                                     int* __restrict__ cursor,
                                     int* __restrict__ csr) {
    int e = blockIdx.x * blockDim.x + threadIdx.x;
    if (e >= N_EDGES) return;
    int s = ei[e];
    int d = ei[N_EDGES + e];
    int pos = atomicAdd(&cursor[d], 1);
    csr[pos] = s;
}

// ---------- K4: gather-aggregate (NO atomics): aggh[n] = sum xh[src] ----------
__global__ void gather_agg_kernel(const half8* __restrict__ xh8,
                                  const int* __restrict__ row_start,
                                  const int* __restrict__ csr,
                                  half8* __restrict__ aggh8) {
    int idx = blockIdx.x * blockDim.x + threadIdx.x;   // < N*24
    int n = idx / 24;
    int p = idx - n * 24;
    int e0 = row_start[n], e1 = row_start[n + 1];
    half8 acc = {0, 0, 0, 0, 0, 0, 0, 0};
    half8 acc2 = {0, 0, 0, 0, 0, 0, 0, 0};
    int e = e0;
    for (; e + 2 <= e1; e += 2) {
        int s0 = csr[e], s1 = csr[e + 1];
        half8 v0 = xh8[(long)s0 * 24 + p];
        half8 v1 = xh8[(long)s1 * 24 + p];
        acc += v0;
        acc2 += v1;
    }
    if (e < e1) acc += xh8[(long)csr[e] * 24 + p];
    aggh8[idx] = acc + acc2;
}

// ---------- K5: pack [w1_l | w1_r] (f16) into MFMA fragment order ----------
// lane -> (n = lane&15, k = (lane>>4)*8 + q). Used as A-operand in the swapped GEMM.
__global__ void prep_bfrag_kernel(const float* __restrict__ w1l,
                                  const float* __restrict__ w1r,
                                  _Float16* __restrict__ bfrag) {
    int gid = blockIdx.x * blockDim.x + threadIdx.x;
    if (gid >= 12 * 16 * 64) return;
    int lane = gid & 63;
    int j = (gid >> 6) & 15;
    int c = gid >> 10;
    int quad = lane >> 4, n = lane & 15;
    const float* w = (c < 6) ? w1l : w1r;
    int kb = (c < 6 ? c : c - 6) * 32;
    int col = j * 16 + n;
    half8 r;
#pragma unroll
    for (int q = 0; q < 8; ++q) {
        int k = kb + quad * 8 + q;
        r[q] = (_Float16)((k < F_IN) ? w[k * HID + col] : 0.0f);
    }
    *(half8*)(bfrag + gid * 8) = r;
}

// ---------- K6: fused MFMA GEMM + invdeg + bias + relu + layer-2 projection ----------
// Round-6 structure: reg-staged pipeline (T14) -- NO vmcnt in the main loop at all.
//   iter t: ds_write(As[t&1], r);  r = global_load(pair t+1);  lgkmcnt(0); barrier;
//           compute pair t (ds_read + MFMA).
// The global load has a full compute phase of latency cover and flies ACROSS the
// barrier; the compiler inserts its own counted vmcnt before the consuming ds_write.
// Single barrier/iter is safe with 2 buffers (a wave is at most 1 barrier ahead).
// Epilogue de-pressurized (round-5 spill fix): b1/w2l/w2r staged in a 5KB LDS table
// (quad-uniform reads = broadcast), nt-outer loop keeps only 4 scalars live.
// 64-node block, 8 waves, acc[2][4]=32 AGPR; __launch_bounds__(512,6) = 3 blocks/CU.
__global__ __launch_bounds__(512, 6) void gemm_fused_kernel(
        const _Float16* __restrict__ xh, const _Float16* __restrict__ aggh,
        const float* __restrict__ invdeg, const _Float16* __restrict__ bfrag,
        const float* __restrict__ b1,
        const float* __restrict__ w2l, const float* __restrict__ w2r,
        float* __restrict__ tl, float* __restrict__ tr) {
    __shared__ __attribute__((aligned(16))) _Float16 As[2][4096];  // 2 pair-buffers x 8KB
    __shared__ float wtab[1280];   // [0,256)=b1, [256,768)=w2l, [768,1280)=w2r
    __shared__ float tlr[64][4];
    const int tid = threadIdx.x;
    const int w = tid >> 6, lane = tid & 63;
    const int quad = lane >> 4, l15 = lane & 15;
    const int rowbase = blockIdx.x * 64;          // 3125 * 64 == 200000 exactly

    if (tid < 256) ((float*)tlr)[tid] = 0.0f;
    // stage the layer-2 tables into LDS (visible after the first in-loop barrier)
#pragma unroll
    for (int q = tid; q < 1280; q += 512)
        wtab[q] = (q < 256) ? b1[q] : ((q < 768) ? w2l[q - 256] : w2r[q - 768]);

    // staging map: 512 threads cover one 8KB pair (2 chunks x 256 slots x 16B).
    // slot s = tid&255 -> (row = s>>2, seg = (s&3) ^ ((row>>1)&3)); chunk su = tid>>8.
    const int s = tid & 255;
    const int su = tid >> 8;                       // wave-uniform (waves 0-3 -> 0, 4-7 -> 1)
    const int srow_l = s >> 2;
    const int sseg = (s & 3) ^ ((srow_l >> 1) & 3);
    const int sgoff = (rowbase + srow_l) * SX + sseg * 8;   // halfs
    const int sdst = su * 4096 + s * 16;                    // LDS byte offset within a pair buffer

    // node-fragment LDS byte offsets within one 4KB chunk (read side of the XOR swizzle)
    int aoff[4];
#pragma unroll
    for (int nt = 0; nt < 4; ++nt) {
        int r = nt * 16 + l15;
        int slot = r * 4 + (quad ^ ((r >> 1) & 3));
        aoff[nt] = slot * 16;
    }
    // bfrag: wave w owns hid tiles {2w, 2w+1}
    const int boff = (2 * w * 64 + lane) * 16;

    // invdeg preload (per-lane scalar per node tile)
    float iv[4];
#pragma unroll
    for (int nt = 0; nt < 4; ++nt)
        iv[nt] = invdeg[rowbase + nt * 16 + l15];

    floatx4 acc[2][4];   // [i = hid tile][nt = node tile] : 32 AGPR
#pragma unroll
    for (int i = 0; i < 2; ++i)
#pragma unroll
        for (int nt = 0; nt < 4; ++nt)
            acc[i][nt] = (floatx4){0.f, 0.f, 0.f, 0.f};

    auto LOADG = [&](int p) -> half8 {
        const int cc = 2 * p + su;
        const _Float16* src = (cc < 6) ? aggh : xh;          // wave-uniform select
        const int kb = (cc < 6 ? cc : cc - 6) * 32;
        return *(const half8*)(src + sgoff + kb);
    };

    half8 r = LOADG(0);   // pair-0 staging data in flight

#pragma unroll 1
    for (int t = 0; t < 6; ++t) {
        // write the staged pair into LDS (compiler inserts the vmcnt wait for r)
        *(half8*)((char*)(&As[t & 1][0]) + sdst) = r;
        if (t < 5) r = LOADG(t + 1);               // next pair's HBM load flies under compute
        asm volatile("s_waitcnt lgkmcnt(0)" ::: "memory");
        __builtin_amdgcn_s_barrier();
        __builtin_amdgcn_sched_barrier(0);

        const char* abase = (const char*)(&As[t & 1][0]);
#pragma unroll
        for (int u = 0; u < 2; ++u) {
            const int cc = 2 * t + u;
            half8 a[4], b[2];
#pragma unroll
            for (int nt = 0; nt < 4; ++nt)
                a[nt] = *(const half8*)(abase + u * 4096 + aoff[nt]);
#pragma unroll
            for (int i = 0; i < 2; ++i)
                b[i] = *(const half8*)((const char*)bfrag + boff + (cc * 16 + i) * 1024);
#pragma unroll
            for (int i = 0; i < 2; ++i)
#pragma unroll
                for (int nt = 0; nt < 4; ++nt)
                    acc[i][nt] = __builtin_amdgcn_mfma_f32_16x16x32_f16(b[i], a[nt], acc[i][nt], 0, 0, 0);
        }
        if (t == 2) {   // agg phase (cc 0..5) done: scale by preloaded invdeg
#pragma unroll
            for (int nt = 0; nt < 4; ++nt)
#pragma unroll
                for (int i = 0; i < 2; ++i)
                    acc[i][nt] *= iv[nt];
        }
    }
    __syncthreads();   // all waves done with compute (and LDS tables fully written)

    // ---- epilogue: nt-outer, tables from LDS (quad-uniform -> broadcast reads) ----
    const float* bt  = wtab;
    const float* wlt = wtab + 256;
    const float* wrt = wtab + 768;
#pragma unroll
    for (int nt = 0; nt < 4; ++nt) {
        float s0 = 0.f, s1 = 0.f, s2 = 0.f, s3 = 0.f;
#pragma unroll
        for (int i = 0; i < 2; ++i) {
            const int j0 = w * 32 + i * 16 + quad * 4;
#pragma unroll
            for (int reg = 0; reg < 4; ++reg) {
                const int j = j0 + reg;
                float v = fmaxf(acc[i][nt][reg] + bt[j], 0.0f);
                s0 += v * wlt[2 * j];
                s1 += v * wlt[2 * j + 1];
                s2 += v * wrt[2 * j];
                s3 += v * wrt[2 * j + 1];
            }
        }
        s0 += __shfl_xor(s0, 16, 64); s0 += __shfl_xor(s0, 32, 64);
        s1 += __shfl_xor(s1, 16, 64); s1 += __shfl_xor(s1, 32, 64);
        s2 += __shfl_xor(s2, 16, 64); s2 += __shfl_xor(s2, 32, 64);
        s3 += __shfl_xor(s3, 16, 64); s3 += __shfl_xor(s3, 32, 64);
        if (quad == 0) {   // lanes 0..15 hold the wave's 32-hid partial for node row
            int rl = nt * 16 + l15;
            atomicAdd(&tlr[rl][0], s0);
            atomicAdd(&tlr[rl][1], s1);
            atomicAdd(&tlr[rl][2], s2);
            atomicAdd(&tlr[rl][3], s3);
        }
    }
    __syncthreads();
    if (tid < 64) {
        int row = rowbase + tid;
        tl[row * 2 + 0] = tlr[tid][0];
        tl[row * 2 + 1] = tlr[tid][1];
        tr[row * 2 + 0] = tlr[tid][2];
        tr[row * 2 + 1] = tlr[tid][3];
    }
}

// ---------- K7: fused layer-2 gather + finalize (NO atomics) ----------
__global__ void gather_out_kernel(const int* __restrict__ row_start,
                                  const int* __restrict__ csr,
                                  const float* __restrict__ tl,
                                  const float* __restrict__ tr,
                                  const float* __restrict__ invdeg,
                                  const float* __restrict__ b2,
                                  float* __restrict__ out) {
    int i = blockIdx.x * blockDim.x + threadIdx.x;
    if (i >= N_NODES) return;
    int e0 = row_start[i], e1 = row_start[i + 1];
    float a0 = 0.f, a1 = 0.f;
    for (int e = e0; e < e1; ++e) {
        int s = csr[e];
        a0 += tl[s * 2 + 0];
        a1 += tl[s * 2 + 1];
    }
    float inv = invdeg[i];
    out[i * 2 + 0] = a0 * inv + tr[i * 2 + 0] + b2[0];
    out[i * 2 + 1] = a1 * inv + tr[i * 2 + 1] + b2[1];
}

// ---------- K8: edge_index -> f32 passthrough ----------
__global__ void cast_edges_kernel(const int* __restrict__ ei,
                                  float* __restrict__ out) {
    int i = blockIdx.x * blockDim.x + threadIdx.x;
    if (i < 2 * N_EDGES) out[i] = (float)ei[i];
}

// ---------- workspace layout (bytes) ----------
//   0          degi      800000   (memset 0)
//   800000     row_start 800016   (N+1 ints)
//   1600032    cursor    800000
//   2400032    invdeg    800000
//   3200032    csr       2000000
//   5200032    tl        1600000
//   6800032    tr        1600000
//   8400032    bsum      3200
//   8403232    boff      3200
//   8406432    bfrag     196608
//   8610000    aggh      76800000  (f16, stride SX)
//   85410000   xh        76800000  (f16, stride SX)
extern "C" void kernel_launch(void* const* d_in, const int* in_sizes, int n_in,
                              void* d_out, int out_size, void* d_ws, size_t ws_size,
                              hipStream_t stream) {
    const float* x    = (const float*)d_in[0];
    const int*   ei   = (const int*)d_in[1];
    const float* w1_l = (const float*)d_in[2];
    const float* w1_r = (const float*)d_in[3];
    const float* b1   = (const float*)d_in[4];
    const float* w2_l = (const float*)d_in[5];
    const float* w2_r = (const float*)d_in[6];
    const float* b2   = (const float*)d_in[7];

    char* ws = (char*)d_ws;
    int*   degi      = (int*)(ws);
    int*   row_start = (int*)(ws + 800000);
    int*   cursor    = (int*)(ws + 1600032);
    float* invdeg    = (float*)(ws + 2400032);
    int*   csr       = (int*)(ws + 3200032);
    float* tl        = (float*)(ws + 5200032);
    float* tr        = (float*)(ws + 6800032);
    int*   bsum      = (int*)(ws + 8400032);
    int*   boff      = (int*)(ws + 8403232);
    _Float16* bfrag  = (_Float16*)(ws + 8406432);
    _Float16* aggh   = (_Float16*)(ws + 8610000);
    _Float16* xh     = (_Float16*)(ws + 85410000);

    float* out = (float*)d_out;   // f32: logits [0,400000), edges [400000,1400000)

    (void)hipMemsetAsync(degi, 0, 800000, stream);

    cast_x_kernel<<<(N_NODES * 24) / 256, 256, 0, stream>>>(x, (half8*)xh);
    prep_bfrag_kernel<<<48, 256, 0, stream>>>(w1_l, w1_r, bfrag);

    hist_kernel<<<(N_EDGES + 255) / 256, 256, 0, stream>>>(ei, degi);
    block_sum_kernel<<<NB, 256, 0, stream>>>(degi, bsum);
    scan_bsum_kernel<<<1, 1024, 0, stream>>>(bsum, boff, row_start);
    scan_emit_kernel<<<NB, 256, 0, stream>>>(degi, boff, row_start, cursor, invdeg);
    scatter_edges_kernel<<<(N_EDGES + 255) / 256, 256, 0, stream>>>(ei, cursor, csr);

    gather_agg_kernel<<<(N_NODES * 24) / 256, 256, 0, stream>>>(
        (const half8*)xh, row_start, csr, (half8*)aggh);

    gemm_fused_kernel<<<N_NODES / 64, 512, 0, stream>>>(
        xh, aggh, invdeg, bfrag, b1, w2_l, w2_r, tl, tr);

    gather_out_kernel<<<NB, 256, 0, stream>>>(row_start, csr, tl, tr, invdeg, b2, out);
    cast_edges_kernel<<<(2 * N_EDGES + 255) / 256, 256, 0, stream>>>(ei, out + 2 * N_NODES);
}

// Round 7
// 426.751 us; speedup vs baseline: 1.0406x; 1.0406x over previous
//
#include <hip/hip_runtime.h>
#include <hip/hip_bf16.h>
#include <hip/hip_fp16.h>

#define N_NODES 200000
#define N_EDGES 500000
#define F_IN    165
#define HID     256
#define SX      192   // padded f16 row stride (24 half8 segs, 16B-aligned rows)
#define NB      782   // ceil(N_NODES/256) scan blocks

typedef float    floatx4 __attribute__((ext_vector_type(4)));
typedef float    floatx4a __attribute__((ext_vector_type(4), aligned(16)));
typedef float    float4u __attribute__((ext_vector_type(4), aligned(4)));
typedef _Float16 half8   __attribute__((ext_vector_type(8)));

// ---------- K0: x (f32, stride 165) -> xh (f16 half8 segs, stride 24) ----------
__global__ void cast_x_kernel(const float* __restrict__ x, half8* __restrict__ xh8) {
    int idx = blockIdx.x * blockDim.x + threadIdx.x;   // < N*24
    int row = idx / 24;
    int p = idx - row * 24;
    int f0 = p * 8;
    const float* px = x + (long)row * F_IN + f0;
    half8 r;
    if (f0 + 8 <= F_IN) {
        float4u lo = *(const float4u*)px;
        float4u hi = *(const float4u*)(px + 4);
#pragma unroll
        for (int q = 0; q < 4; ++q) r[q] = (_Float16)lo[q];
#pragma unroll
        for (int q = 0; q < 4; ++q) r[4 + q] = (_Float16)hi[q];
    } else {
#pragma unroll
        for (int q = 0; q < 8; ++q)
            r[q] = (f0 + q < F_IN) ? (_Float16)px[q] : (_Float16)0.0f;
    }
    xh8[idx] = r;
}

// ---------- K1: dst-degree histogram ----------
__global__ void hist_kernel(const int* __restrict__ ei, int* __restrict__ degi) {
    int e = blockIdx.x * blockDim.x + threadIdx.x;
    if (e < N_EDGES) atomicAdd(&degi[ei[N_EDGES + e]], 1);
}

// ---------- K2a: per-block degree sums ----------
__global__ __launch_bounds__(256) void block_sum_kernel(const int* __restrict__ degi,
                                                        int* __restrict__ bsum) {
    __shared__ int sh[256];
    int t = threadIdx.x, i = blockIdx.x * 256 + t;
    sh[t] = (i < N_NODES) ? degi[i] : 0;
    __syncthreads();
#pragma unroll
    for (int off = 128; off > 0; off >>= 1) {
        if (t < off) sh[t] += sh[t + off];
        __syncthreads();
    }
    if (t == 0) bsum[blockIdx.x] = sh[0];
}

// ---------- K2b: scan the 782 block sums (1 block) ----------
__global__ __launch_bounds__(1024) void scan_bsum_kernel(const int* __restrict__ bsum,
                                                         int* __restrict__ boff,
                                                         int* __restrict__ row_start) {
    __shared__ int sh[1024];
    int t = threadIdx.x;
    int v = (t < NB) ? bsum[t] : 0;
    sh[t] = v;
    __syncthreads();
    for (int off = 1; off < 1024; off <<= 1) {
        int u = (t >= off) ? sh[t - off] : 0;
        __syncthreads();
        sh[t] += u;
        __syncthreads();
    }
    if (t < NB) boff[t] = sh[t] - v;               // exclusive
    if (t == 1023) row_start[N_NODES] = sh[1023];  // total = E
}

// ---------- K2c: emit row_start / cursor / invdeg ----------
__global__ __launch_bounds__(256) void scan_emit_kernel(const int* __restrict__ degi,
                                                        const int* __restrict__ boff,
                                                        int* __restrict__ row_start,
                                                        int* __restrict__ cursor,
                                                        float* __restrict__ invdeg) {
    __shared__ int sh[256];
    int t = threadIdx.x, i = blockIdx.x * 256 + t;
    int d = (i < N_NODES) ? degi[i] : 0;
    sh[t] = d;
    __syncthreads();
#pragma unroll
    for (int off = 1; off < 256; off <<= 1) {
        int u = (t >= off) ? sh[t - off] : 0;
        __syncthreads();
        sh[t] += u;
        __syncthreads();
    }
    if (i < N_NODES) {
        int row = boff[blockIdx.x] + sh[t] - d;    // exclusive scan value
        row_start[i] = row;
        cursor[i] = row;
        invdeg[i] = 1.0f / fmaxf((float)d, 1.0f);
    }
}

// ---------- K3: bucket edges into CSR ----------
__global__ void scatter_edges_kernel(const int* __restrict__ ei,
                                     int* __restrict__ cursor,
                                     int* __restrict__ csr) {
    int e = blockIdx.x * blockDim.x + threadIdx.x;
    if (e >= N_EDGES) return;
    int s = ei[e];
    int d = ei[N_EDGES + e];
    int pos = atomicAdd(&cursor[d], 1);
    csr[pos] = s;
}

// ---------- K5: pack [w1_l | w1_r] (f16) into MFMA fragment order ----------
// lane -> (n = lane&15, k = (lane>>4)*8 + q). Used as A-operand in the swapped GEMM.
__global__ void prep_bfrag_kernel(const float* __restrict__ w1l,
                                  const float* __restrict__ w1r,
                                  _Float16* __restrict__ bfrag) {
    int gid = blockIdx.x * blockDim.x + threadIdx.x;
    if (gid >= 12 * 16 * 64) return;
    int lane = gid & 63;
    int j = (gid >> 6) & 15;
    int c = gid >> 10;
    int quad = lane >> 4, n = lane & 15;
    const float* w = (c < 6) ? w1l : w1r;
    int kb = (c < 6 ? c : c - 6) * 32;
    int col = j * 16 + n;
    half8 r;
#pragma unroll
    for (int q = 0; q < 8; ++q) {
        int k = kb + quad * 8 + q;
        r[q] = (_Float16)((k < F_IN) ? w[k * HID + col] : 0.0f);
    }
    *(half8*)(bfrag + gid * 8) = r;
}

// ---------- K6: FUSED gather-agg + MFMA GEMM + invdeg + bias + relu + layer-2 ----------
// Round-7: the mean-aggregation is computed INSIDE the staging phase, killing the
// aggh round-trip (76.8MB write + 38.4MB read HBM) and the gather_agg dispatch.
//   pairs 0..2 (agg): staging thread (row n, seg) computes r = sum_e xh[csr[e]] seg
//                     (deg~2.5 f16 adds, xh is L3-resident) then ds_write.
//   pairs 3..5 (root): r = single xh load, ds_write.
// Uniform reg->LDS staging => NO vmcnt anywhere; one lgkmcnt(0)+barrier per pair
// (2 buffers, single barrier is safe: a wave is at most 1 barrier ahead).
// __launch_bounds__(512,4): cap 128 regs (32 AGPR acc + ~80 arch) -> NO spill
// (rounds 5/6 spilled at the (512,6) cap=85; occupancy self-selects 2-3 blocks/CU).
__global__ __launch_bounds__(512, 4) void gemm_fused_kernel(
        const _Float16* __restrict__ xh,
        const int* __restrict__ row_start, const int* __restrict__ csr,
        const float* __restrict__ invdeg, const _Float16* __restrict__ bfrag,
        const float* __restrict__ b1,
        const float* __restrict__ w2l, const float* __restrict__ w2r,
        float* __restrict__ tl, float* __restrict__ tr) {
    __shared__ __attribute__((aligned(16))) _Float16 As[2][4096];  // 2 pair-buffers x 8KB
    __shared__ float tlr[64][4];
    const int tid = threadIdx.x;
    const int w = tid >> 6, lane = tid & 63;
    const int quad = lane >> 4, l15 = lane & 15;
    const int rowbase = blockIdx.x * 64;          // 3125 * 64 == 200000 exactly

    if (tid < 256) ((float*)tlr)[tid] = 0.0f;     // ordered by first in-loop barrier

    // staging map: 512 threads cover one 8KB pair (2 chunks x 256 slots x 16B).
    // slot s = tid&255 -> (row = s>>2, seg = (s&3) ^ ((row>>1)&3)); chunk su = tid>>8.
    const int s = tid & 255;
    const int su = tid >> 8;                       // wave-uniform (waves 0-3 -> 0, 4-7 -> 1)
    const int srow_l = s >> 2;
    const int n = rowbase + srow_l;
    const int sseg = (s & 3) ^ ((srow_l >> 1) & 3);
    const int sgoff = n * SX + sseg * 8;           // halfs (root-path source)
    const int sdst = su * 4096 + s * 16;           // LDS byte offset within a pair buffer
    const int e0 = row_start[n], e1 = row_start[n + 1];   // this thread's edge range

    // node-fragment LDS byte offsets within one 4KB chunk (read side of the XOR swizzle)
    int aoff[4];
#pragma unroll
    for (int nt = 0; nt < 4; ++nt) {
        int r = nt * 16 + l15;
        int slot = r * 4 + (quad ^ ((r >> 1) & 3));
        aoff[nt] = slot * 16;
    }
    // bfrag: wave w owns hid tiles {2w, 2w+1}
    const int boff = (2 * w * 64 + lane) * 16;

    // invdeg preload (per-lane scalar per node tile)
    float iv[4];
#pragma unroll
    for (int nt = 0; nt < 4; ++nt)
        iv[nt] = invdeg[rowbase + nt * 16 + l15];

    floatx4 acc[2][4];   // [i = hid tile][nt = node tile] : 32 AGPR
#pragma unroll
    for (int i = 0; i < 2; ++i)
#pragma unroll
        for (int nt = 0; nt < 4; ++nt)
            acc[i][nt] = (floatx4){0.f, 0.f, 0.f, 0.f};

    // agg staging: gather-sum neighbor rows' (seg, chunk) slice from L3-resident xh
    auto GATHER = [&](int p) -> half8 {            // p in 0..2, cc = 2p+su < 6
        const int off = (2 * p + su) * 32 + sseg * 8;     // halfs within a row
        half8 a0 = {0, 0, 0, 0, 0, 0, 0, 0};
        half8 a1 = {0, 0, 0, 0, 0, 0, 0, 0};
        int e = e0;
        for (; e + 2 <= e1; e += 2) {
            int s0 = csr[e], s1 = csr[e + 1];
            a0 += *(const half8*)(xh + s0 * SX + off);
            a1 += *(const half8*)(xh + s1 * SX + off);
        }
        if (e < e1) a0 += *(const half8*)(xh + csr[e] * SX + off);
        return a0 + a1;
    };
    // root staging: direct slice of this block's own rows
    auto LOADR = [&](int p) -> half8 {             // p in 3..5, cc = 2p+su >= 6
        const int kb = (2 * p + su - 6) * 32;
        return *(const half8*)(xh + sgoff + kb);
    };

    half8 r = GATHER(0);   // pair-0 staging data

#pragma unroll 1
    for (int t = 0; t < 6; ++t) {
        *(half8*)((char*)(&As[t & 1][0]) + sdst) = r;     // stage pair t into LDS
        if (t < 5) r = (t < 2) ? GATHER(t + 1) : LOADR(t + 1);  // next pair under compute
        asm volatile("s_waitcnt lgkmcnt(0)" ::: "memory");
        __builtin_amdgcn_s_barrier();
        __builtin_amdgcn_sched_barrier(0);

        const char* abase = (const char*)(&As[t & 1][0]);
#pragma unroll
        for (int u = 0; u < 2; ++u) {
            const int cc = 2 * t + u;
            half8 a[4], b[2];
#pragma unroll
            for (int nt = 0; nt < 4; ++nt)
                a[nt] = *(const half8*)(abase + u * 4096 + aoff[nt]);
#pragma unroll
            for (int i = 0; i < 2; ++i)
                b[i] = *(const half8*)((const char*)bfrag + boff + (cc * 16 + i) * 1024);
#pragma unroll
            for (int i = 0; i < 2; ++i)
#pragma unroll
                for (int nt = 0; nt < 4; ++nt)
                    acc[i][nt] = __builtin_amdgcn_mfma_f32_16x16x32_f16(b[i], a[nt], acc[i][nt], 0, 0, 0);
        }
        if (t == 2) {   // agg phase (cc 0..5) done: scale by preloaded invdeg
#pragma unroll
            for (int nt = 0; nt < 4; ++nt)
#pragma unroll
                for (int i = 0; i < 2; ++i)
                    acc[i][nt] *= iv[nt];
        }
    }

    // ---- epilogue: hid-reduction per-lane; 2 shfl steps across quads ----
    float sacc[4][4];   // [nt][c] : c = {tl0, tl1, tr0, tr1}
#pragma unroll
    for (int nt = 0; nt < 4; ++nt)
#pragma unroll
        for (int c = 0; c < 4; ++c) sacc[nt][c] = 0.0f;

#pragma unroll
    for (int i = 0; i < 2; ++i) {
        const int j0 = w * 32 + i * 16 + quad * 4;   // this lane's 4 hid cols (reg 0..3)
        floatx4a bbv = *(const floatx4a*)(b1 + j0);
        floatx4a wlA = *(const floatx4a*)(w2l + j0 * 2);      // [j0][0],[j0][1],[j0+1][0],[j0+1][1]
        floatx4a wlB = *(const floatx4a*)(w2l + j0 * 2 + 4);  // [j0+2..j0+3]
        floatx4a wrA = *(const floatx4a*)(w2r + j0 * 2);
        floatx4a wrB = *(const floatx4a*)(w2r + j0 * 2 + 4);
#pragma unroll
        for (int nt = 0; nt < 4; ++nt) {
#pragma unroll
            for (int reg = 0; reg < 4; ++reg) {
                float v = fmaxf(acc[i][nt][reg] + bbv[reg], 0.0f);
                float wl0 = (reg < 2) ? wlA[(reg & 1) * 2]     : wlB[(reg & 1) * 2];
                float wl1 = (reg < 2) ? wlA[(reg & 1) * 2 + 1] : wlB[(reg & 1) * 2 + 1];
                float wr0 = (reg < 2) ? wrA[(reg & 1) * 2]     : wrB[(reg & 1) * 2];
                float wr1 = (reg < 2) ? wrA[(reg & 1) * 2 + 1] : wrB[(reg & 1) * 2 + 1];
                sacc[nt][0] += v * wl0;
                sacc[nt][1] += v * wl1;
                sacc[nt][2] += v * wr0;
                sacc[nt][3] += v * wr1;
            }
        }
    }
#pragma unroll
    for (int nt = 0; nt < 4; ++nt) {
#pragma unroll
        for (int c = 0; c < 4; ++c) {
            sacc[nt][c] += __shfl_xor(sacc[nt][c], 16, 64);
            sacc[nt][c] += __shfl_xor(sacc[nt][c], 32, 64);
        }
        if (quad == 0) {   // lanes 0..15 hold the wave's 32-hid partial for node row
            int rl = nt * 16 + l15;
            atomicAdd(&tlr[rl][0], sacc[nt][0]);
            atomicAdd(&tlr[rl][1], sacc[nt][1]);
            atomicAdd(&tlr[rl][2], sacc[nt][2]);
            atomicAdd(&tlr[rl][3], sacc[nt][3]);
        }
    }
    __syncthreads();
    if (tid < 64) {
        int row = rowbase + tid;
        tl[row * 2 + 0] = tlr[tid][0];
        tl[row * 2 + 1] = tlr[tid][1];
        tr[row * 2 + 0] = tlr[tid][2];
        tr[row * 2 + 1] = tlr[tid][3];
    }
}

// ---------- K7: fused layer-2 gather + finalize (NO atomics) ----------
__global__ void gather_out_kernel(const int* __restrict__ row_start,
                                  const int* __restrict__ csr,
                                  const float* __restrict__ tl,
                                  const float* __restrict__ tr,
                                  const float* __restrict__ invdeg,
                                  const float* __restrict__ b2,
                                  float* __restrict__ out) {
    int i = blockIdx.x * blockDim.x + threadIdx.x;
    if (i >= N_NODES) return;
    int e0 = row_start[i], e1 = row_start[i + 1];
    float a0 = 0.f, a1 = 0.f;
    for (int e = e0; e < e1; ++e) {
        int s = csr[e];
        a0 += tl[s * 2 + 0];
        a1 += tl[s * 2 + 1];
    }
    float inv = invdeg[i];
    out[i * 2 + 0] = a0 * inv + tr[i * 2 + 0] + b2[0];
    out[i * 2 + 1] = a1 * inv + tr[i * 2 + 1] + b2[1];
}

// ---------- K8: edge_index -> f32 passthrough ----------
__global__ void cast_edges_kernel(const int* __restrict__ ei,
                                  float* __restrict__ out) {
    int i = blockIdx.x * blockDim.x + threadIdx.x;
    if (i < 2 * N_EDGES) out[i] = (float)ei[i];
}

// ---------- workspace layout (bytes) ----------
//   0          degi      800000   (memset 0)
//   800000     row_start 800016   (N+1 ints)
//   1600032    cursor    800000
//   2400032    invdeg    800000
//   3200032    csr       2000000
//   5200032    tl        1600000
//   6800032    tr        1600000
//   8400032    bsum      3200
//   8403232    boff      3200
//   8406432    bfrag     196608
//   85410000   xh        76800000  (f16, stride SX)   [aggh slot unused now]
extern "C" void kernel_launch(void* const* d_in, const int* in_sizes, int n_in,
                              void* d_out, int out_size, void* d_ws, size_t ws_size,
                              hipStream_t stream) {
    const float* x    = (const float*)d_in[0];
    const int*   ei   = (const int*)d_in[1];
    const float* w1_l = (const float*)d_in[2];
    const float* w1_r = (const float*)d_in[3];
    const float* b1   = (const float*)d_in[4];
    const float* w2_l = (const float*)d_in[5];
    const float* w2_r = (const float*)d_in[6];
    const float* b2   = (const float*)d_in[7];

    char* ws = (char*)d_ws;
    int*   degi      = (int*)(ws);
    int*   row_start = (int*)(ws + 800000);
    int*   cursor    = (int*)(ws + 1600032);
    float* invdeg    = (float*)(ws + 2400032);
    int*   csr       = (int*)(ws + 3200032);
    float* tl        = (float*)(ws + 5200032);
    float* tr        = (float*)(ws + 6800032);
    int*   bsum      = (int*)(ws + 8400032);
    int*   boff      = (int*)(ws + 8403232);
    _Float16* bfrag  = (_Float16*)(ws + 8406432);
    _Float16* xh     = (_Float16*)(ws + 85410000);

    float* out = (float*)d_out;   // f32: logits [0,400000), edges [400000,1400000)

    (void)hipMemsetAsync(degi, 0, 800000, stream);

    cast_x_kernel<<<(N_NODES * 24) / 256, 256, 0, stream>>>(x, (half8*)xh);
    prep_bfrag_kernel<<<48, 256, 0, stream>>>(w1_l, w1_r, bfrag);

    hist_kernel<<<(N_EDGES + 255) / 256, 256, 0, stream>>>(ei, degi);
    block_sum_kernel<<<NB, 256, 0, stream>>>(degi, bsum);
    scan_bsum_kernel<<<1, 1024, 0, stream>>>(bsum, boff, row_start);
    scan_emit_kernel<<<NB, 256, 0, stream>>>(degi, boff, row_start, cursor, invdeg);
    scatter_edges_kernel<<<(N_EDGES + 255) / 256, 256, 0, stream>>>(ei, cursor, csr);

    gemm_fused_kernel<<<N_NODES / 64, 512, 0, stream>>>(
        xh, row_start, csr, invdeg, bfrag, b1, w2_l, w2_r, tl, tr);

    gather_out_kernel<<<NB, 256, 0, stream>>>(row_start, csr, tl, tr, invdeg, b2, out);
    cast_edges_kernel<<<(2 * N_EDGES + 255) / 256, 256, 0, stream>>>(ei, out + 2 * N_NODES);
}

// Round 8
// 426.747 us; speedup vs baseline: 1.0406x; 1.0000x over previous
//
#include <hip/hip_runtime.h>
#include <hip/hip_bf16.h>
#include <hip/hip_fp16.h>

#define N_NODES 200000
#define N_EDGES 500000
#define F_IN    165
#define HID     256
#define SX      192   // padded f16 row stride (24 half8 segs, 16B-aligned rows)
#define NB      782   // ceil(N_NODES/256) scan blocks

typedef float    floatx4 __attribute__((ext_vector_type(4)));
typedef float    floatx4a __attribute__((ext_vector_type(4), aligned(16)));
typedef float    float4u __attribute__((ext_vector_type(4), aligned(4)));
typedef _Float16 half8   __attribute__((ext_vector_type(8)));

// ---------- K0: x (f32, stride 165) -> xh (f16 half8 segs, stride 24) ----------
__global__ void cast_x_kernel(const float* __restrict__ x, half8* __restrict__ xh8) {
    int idx = blockIdx.x * blockDim.x + threadIdx.x;   // < N*24
    int row = idx / 24;
    int p = idx - row * 24;
    int f0 = p * 8;
    const float* px = x + (long)row * F_IN + f0;
    half8 r;
    if (f0 + 8 <= F_IN) {
        float4u lo = *(const float4u*)px;
        float4u hi = *(const float4u*)(px + 4);
#pragma unroll
        for (int q = 0; q < 4; ++q) r[q] = (_Float16)lo[q];
#pragma unroll
        for (int q = 0; q < 4; ++q) r[4 + q] = (_Float16)hi[q];
    } else {
#pragma unroll
        for (int q = 0; q < 8; ++q)
            r[q] = (f0 + q < F_IN) ? (_Float16)px[q] : (_Float16)0.0f;
    }
    xh8[idx] = r;
}

// ---------- K1: dst-degree histogram ----------
__global__ void hist_kernel(const int* __restrict__ ei, int* __restrict__ degi) {
    int e = blockIdx.x * blockDim.x + threadIdx.x;
    if (e < N_EDGES) atomicAdd(&degi[ei[N_EDGES + e]], 1);
}

// ---------- K2a: per-block degree sums ----------
__global__ __launch_bounds__(256) void block_sum_kernel(const int* __restrict__ degi,
                                                        int* __restrict__ bsum) {
    __shared__ int sh[256];
    int t = threadIdx.x, i = blockIdx.x * 256 + t;
    sh[t] = (i < N_NODES) ? degi[i] : 0;
    __syncthreads();
#pragma unroll
    for (int off = 128; off > 0; off >>= 1) {
        if (t < off) sh[t] += sh[t + off];
        __syncthreads();
    }
    if (t == 0) bsum[blockIdx.x] = sh[0];
}

// ---------- K2b: scan the 782 block sums (1 block) ----------
__global__ __launch_bounds__(1024) void scan_bsum_kernel(const int* __restrict__ bsum,
                                                         int* __restrict__ boff,
                                                         int* __restrict__ row_start) {
    __shared__ int sh[1024];
    int t = threadIdx.x;
    int v = (t < NB) ? bsum[t] : 0;
    sh[t] = v;
    __syncthreads();
    for (int off = 1; off < 1024; off <<= 1) {
        int u = (t >= off) ? sh[t - off] : 0;
        __syncthreads();
        sh[t] += u;
        __syncthreads();
    }
    if (t < NB) boff[t] = sh[t] - v;               // exclusive
    if (t == 1023) row_start[N_NODES] = sh[1023];  // total = E
}

// ---------- K2c: emit row_start / cursor / invdeg ----------
__global__ __launch_bounds__(256) void scan_emit_kernel(const int* __restrict__ degi,
                                                        const int* __restrict__ boff,
                                                        int* __restrict__ row_start,
                                                        int* __restrict__ cursor,
                                                        float* __restrict__ invdeg) {
    __shared__ int sh[256];
    int t = threadIdx.x, i = blockIdx.x * 256 + t;
    int d = (i < N_NODES) ? degi[i] : 0;
    sh[t] = d;
    __syncthreads();
#pragma unroll
    for (int off = 1; off < 256; off <<= 1) {
        int u = (t >= off) ? sh[t - off] : 0;
        __syncthreads();
        sh[t] += u;
        __syncthreads();
    }
    if (i < N_NODES) {
        int row = boff[blockIdx.x] + sh[t] - d;    // exclusive scan value
        row_start[i] = row;
        cursor[i] = row;
        invdeg[i] = 1.0f / fmaxf((float)d, 1.0f);
    }
}

// ---------- K3: bucket edges into CSR ----------
__global__ void scatter_edges_kernel(const int* __restrict__ ei,
                                     int* __restrict__ cursor,
                                     int* __restrict__ csr) {
    int e = blockIdx.x * blockDim.x + threadIdx.x;
    if (e >= N_EDGES) return;
    int s = ei[e];
    int d = ei[N_EDGES + e];
    int pos = atomicAdd(&cursor[d], 1);
    csr[pos] = s;
}

// ---------- K4: gather-aggregate (NO atomics): aggh[n] = sum xh[src] ----------
__global__ void gather_agg_kernel(const half8* __restrict__ xh8,
                                  const int* __restrict__ row_start,
                                  const int* __restrict__ csr,
                                  half8* __restrict__ aggh8) {
    int idx = blockIdx.x * blockDim.x + threadIdx.x;   // < N*24
    int n = idx / 24;
    int p = idx - n * 24;
    int e0 = row_start[n], e1 = row_start[n + 1];
    half8 acc = {0, 0, 0, 0, 0, 0, 0, 0};
    half8 acc2 = {0, 0, 0, 0, 0, 0, 0, 0};
    int e = e0;
    for (; e + 2 <= e1; e += 2) {
        int s0 = csr[e], s1 = csr[e + 1];
        half8 v0 = xh8[(long)s0 * 24 + p];
        half8 v1 = xh8[(long)s1 * 24 + p];
        acc += v0;
        acc2 += v1;
    }
    if (e < e1) acc += xh8[(long)csr[e] * 24 + p];
    aggh8[idx] = acc + acc2;
}

// ---------- K5: pack [w1_l | w1_r] (f16) into MFMA fragment order ----------
// lane -> (n = lane&15, k = (lane>>4)*8 + q). Used as A-operand in the swapped GEMM.
__global__ void prep_bfrag_kernel(const float* __restrict__ w1l,
                                  const float* __restrict__ w1r,
                                  _Float16* __restrict__ bfrag) {
    int gid = blockIdx.x * blockDim.x + threadIdx.x;
    if (gid >= 12 * 16 * 64) return;
    int lane = gid & 63;
    int j = (gid >> 6) & 15;
    int c = gid >> 10;
    int quad = lane >> 4, n = lane & 15;
    const float* w = (c < 6) ? w1l : w1r;
    int kb = (c < 6 ? c : c - 6) * 32;
    int col = j * 16 + n;
    half8 r;
#pragma unroll
    for (int q = 0; q < 8; ++q) {
        int k = kb + quad * 8 + q;
        r[q] = (_Float16)((k < F_IN) ? w[k * HID + col] : 0.0f);
    }
    *(half8*)(bfrag + gid * 8) = r;
}

// ---------- K6: fused MFMA GEMM + invdeg + bias + relu + layer-2 projection ----------
// Round-8 = the untested clean cell of the spill/occupancy matrix:
//   round-5 DMA staging (global_load_lds, 64-node block, acc[2][4]=32 AGPR,
//   vmcnt(0)+barrier per pair, NO register-held staging data, no asm pinning)
// + round-6 wtab LDS epilogue (b1/w2l/w2r read from LDS broadcast; epilogue
//   live-set ~21 regs instead of ~20 table registers that spilled in r3-r5).
// At __launch_bounds__(512,6) (cap 85 regs incl. AGPR) this should fit WITHOUT
// scratch: main loop ~40 arch V + 32 AGPR; epilogue lean. 3 blocks/CU doubles
// the independent staging streams vs the 2-block baseline (r5 proved occupancy
// 37->55% => BW 860->1333 GB/s proportional; it lost only to the spill tax).
__global__ __launch_bounds__(512, 6) void gemm_fused_kernel(
        const _Float16* __restrict__ xh, const _Float16* __restrict__ aggh,
        const float* __restrict__ invdeg, const _Float16* __restrict__ bfrag,
        const float* __restrict__ b1,
        const float* __restrict__ w2l, const float* __restrict__ w2r,
        float* __restrict__ tl, float* __restrict__ tr) {
    __shared__ __attribute__((aligned(16))) _Float16 As[2][4096];  // 2 pair-buffers x 8KB
    __shared__ float wtab[1280];   // [0,256)=b1, [256,768)=w2l, [768,1280)=w2r
    __shared__ float tlr[64][4];
    const int tid = threadIdx.x;
    const int w = tid >> 6, lane = tid & 63;
    const int quad = lane >> 4, l15 = lane & 15;
    const int rowbase = blockIdx.x * 64;          // 3125 * 64 == 200000 exactly

    if (tid < 256) ((float*)tlr)[tid] = 0.0f;
#pragma unroll
    for (int q = tid; q < 1280; q += 512)
        wtab[q] = (q < 256) ? b1[q] : ((q < 768) ? w2l[q - 256] : w2r[q - 768]);

    // staging map: 512 threads cover one 8KB pair (2 chunks x 256 slots x 16B).
    // slot s = tid&255 -> (row = s>>2, seg = (s&3) ^ ((row>>1)&3)); chunk su = tid>>8.
    const int s = tid & 255;
    const int su = tid >> 8;                       // wave-uniform (waves 0-3 -> 0, 4-7 -> 1)
    const int srow_l = s >> 2;
    const int sseg = (s & 3) ^ ((srow_l >> 1) & 3);
    const int sgoff = (rowbase + srow_l) * SX + sseg * 8;   // halfs
    const int ldst = su * 4096 + (w & 3) * 1024;            // bytes; wave-uniform base

    // node-fragment LDS byte offsets within one 4KB chunk (read side of the XOR swizzle)
    int aoff[4];
#pragma unroll
    for (int nt = 0; nt < 4; ++nt) {
        int r = nt * 16 + l15;
        int slot = r * 4 + (quad ^ ((r >> 1) & 3));
        aoff[nt] = slot * 16;
    }
    // bfrag: wave w owns hid tiles {2w, 2w+1}
    const int boff = (2 * w * 64 + lane) * 16;

    // invdeg preload (per-lane scalar per node tile) -- no loads inside the main loop
    float iv[4];
#pragma unroll
    for (int nt = 0; nt < 4; ++nt)
        iv[nt] = invdeg[rowbase + nt * 16 + l15];

    floatx4 acc[2][4];   // [i = hid tile][nt = node tile] : 32 AGPR
#pragma unroll
    for (int i = 0; i < 2; ++i)
#pragma unroll
        for (int nt = 0; nt < 4; ++nt)
            acc[i][nt] = (floatx4){0.f, 0.f, 0.f, 0.f};

    auto STAGE = [&](int p) {
        const int cc = 2 * p + su;
        const _Float16* src = (cc < 6) ? aggh : xh;          // wave-uniform select
        const int kb = (cc < 6 ? cc : cc - 6) * 32;
        const _Float16* gp = src + sgoff + kb;
        char* dst = (char*)(&As[p & 1][0]) + ldst;
        __builtin_amdgcn_global_load_lds(
            (const __attribute__((address_space(1))) void*)gp,
            (__attribute__((address_space(3))) void*)dst, 16, 0, 0);
    };

    // ---- prologue: stage pair 0; drain DMA + LDS-init writes; barrier ----
    STAGE(0);
    asm volatile("s_waitcnt vmcnt(0) lgkmcnt(0)" ::: "memory");
    __builtin_amdgcn_s_barrier();
    __builtin_amdgcn_sched_barrier(0);

#pragma unroll 1
    for (int t = 0; t < 6; ++t) {
        if (t < 5) STAGE(t + 1);                   // next pair's DMA flies under MFMAs
        const char* abase = (const char*)(&As[t & 1][0]);
#pragma unroll
        for (int u = 0; u < 2; ++u) {
            const int cc = 2 * t + u;
            half8 a[4], b[2];
#pragma unroll
            for (int nt = 0; nt < 4; ++nt)
                a[nt] = *(const half8*)(abase + u * 4096 + aoff[nt]);
#pragma unroll
            for (int i = 0; i < 2; ++i)
                b[i] = *(const half8*)((const char*)bfrag + boff + (cc * 16 + i) * 1024);
#pragma unroll
            for (int i = 0; i < 2; ++i)
#pragma unroll
                for (int nt = 0; nt < 4; ++nt)
                    acc[i][nt] = __builtin_amdgcn_mfma_f32_16x16x32_f16(b[i], a[nt], acc[i][nt], 0, 0, 0);
        }
        if (t == 2) {   // agg phase (cc 0..5) done: scale by preloaded invdeg
#pragma unroll
            for (int nt = 0; nt < 4; ++nt)
#pragma unroll
                for (int i = 0; i < 2; ++i)
                    acc[i][nt] *= iv[nt];
        }
        // next pair's DMA landed + all waves done reading current pair
        asm volatile("s_waitcnt vmcnt(0)" ::: "memory");
        __builtin_amdgcn_s_barrier();
        __builtin_amdgcn_sched_barrier(0);
    }

    // ---- epilogue: tables from LDS (quad-uniform -> broadcast); lean live-set ----
    const float* bt  = wtab;
    const float* wlt = wtab + 256;
    const float* wrt = wtab + 768;
    float sacc[4][4];   // [nt][c] : c = {tl0, tl1, tr0, tr1}
#pragma unroll
    for (int nt = 0; nt < 4; ++nt)
#pragma unroll
        for (int c = 0; c < 4; ++c) sacc[nt][c] = 0.0f;

#pragma unroll
    for (int i = 0; i < 2; ++i) {
        const int j0 = w * 32 + i * 16 + quad * 4;   // this lane's 4 hid cols (reg 0..3)
#pragma unroll
        for (int reg = 0; reg < 4; ++reg) {
            const int j = j0 + reg;
            float bb = bt[j];
            float2 wl = *(const float2*)(wlt + 2 * j);
            float2 wr = *(const float2*)(wrt + 2 * j);
#pragma unroll
            for (int nt = 0; nt < 4; ++nt) {
                float v = fmaxf(acc[i][nt][reg] + bb, 0.0f);
                sacc[nt][0] += v * wl.x;
                sacc[nt][1] += v * wl.y;
                sacc[nt][2] += v * wr.x;
                sacc[nt][3] += v * wr.y;
            }
        }
    }
#pragma unroll
    for (int nt = 0; nt < 4; ++nt) {
#pragma unroll
        for (int c = 0; c < 4; ++c) {
            sacc[nt][c] += __shfl_xor(sacc[nt][c], 16, 64);
            sacc[nt][c] += __shfl_xor(sacc[nt][c], 32, 64);
        }
        if (quad == 0) {   // lanes 0..15 hold the wave's 32-hid partial for node row
            int rl = nt * 16 + l15;
            atomicAdd(&tlr[rl][0], sacc[nt][0]);
            atomicAdd(&tlr[rl][1], sacc[nt][1]);
            atomicAdd(&tlr[rl][2], sacc[nt][2]);
            atomicAdd(&tlr[rl][3], sacc[nt][3]);
        }
    }
    __syncthreads();
    if (tid < 64) {
        int row = rowbase + tid;
        tl[row * 2 + 0] = tlr[tid][0];
        tl[row * 2 + 1] = tlr[tid][1];
        tr[row * 2 + 0] = tlr[tid][2];
        tr[row * 2 + 1] = tlr[tid][3];
    }
}

// ---------- K7: fused layer-2 gather + finalize + edge passthrough ----------
__global__ void gather_out_kernel(const int* __restrict__ row_start,
                                  const int* __restrict__ csr,
                                  const float* __restrict__ tl,
                                  const float* __restrict__ tr,
                                  const float* __restrict__ invdeg,
                                  const float* __restrict__ b2,
                                  const int* __restrict__ ei,
                                  float* __restrict__ out) {
    int i = blockIdx.x * blockDim.x + threadIdx.x;
    if (i < N_NODES) {
        int e0 = row_start[i], e1 = row_start[i + 1];
        float a0 = 0.f, a1 = 0.f;
        for (int e = e0; e < e1; ++e) {
            int s = csr[e];
            a0 += tl[s * 2 + 0];
            a1 += tl[s * 2 + 1];
        }
        float inv = invdeg[i];
        out[i * 2 + 0] = a0 * inv + tr[i * 2 + 0] + b2[0];
        out[i * 2 + 1] = a1 * inv + tr[i * 2 + 1] + b2[1];
    }
    if (i < 2 * N_EDGES) out[2 * N_NODES + i] = (float)ei[i];
}

// ---------- workspace layout (bytes) ----------
//   0          degi      800000   (memset 0)
//   800000     row_start 800016   (N+1 ints)
//   1600032    cursor    800000
//   2400032    invdeg    800000
//   3200032    csr       2000000
//   5200032    tl        1600000
//   6800032    tr        1600000
//   8400032    bsum      3200
//   8403232    boff      3200
//   8406432    bfrag     196608
//   8610000    aggh      76800000  (f16, stride SX)
//   85410000   xh        76800000  (f16, stride SX)
extern "C" void kernel_launch(void* const* d_in, const int* in_sizes, int n_in,
                              void* d_out, int out_size, void* d_ws, size_t ws_size,
                              hipStream_t stream) {
    const float* x    = (const float*)d_in[0];
    const int*   ei   = (const int*)d_in[1];
    const float* w1_l = (const float*)d_in[2];
    const float* w1_r = (const float*)d_in[3];
    const float* b1   = (const float*)d_in[4];
    const float* w2_l = (const float*)d_in[5];
    const float* w2_r = (const float*)d_in[6];
    const float* b2   = (const float*)d_in[7];

    char* ws = (char*)d_ws;
    int*   degi      = (int*)(ws);
    int*   row_start = (int*)(ws + 800000);
    int*   cursor    = (int*)(ws + 1600032);
    float* invdeg    = (float*)(ws + 2400032);
    int*   csr       = (int*)(ws + 3200032);
    float* tl        = (float*)(ws + 5200032);
    float* tr        = (float*)(ws + 6800032);
    int*   bsum      = (int*)(ws + 8400032);
    int*   boff      = (int*)(ws + 8403232);
    _Float16* bfrag  = (_Float16*)(ws + 8406432);
    _Float16* aggh   = (_Float16*)(ws + 8610000);
    _Float16* xh     = (_Float16*)(ws + 85410000);

    float* out = (float*)d_out;   // f32: logits [0,400000), edges [400000,1400000)

    (void)hipMemsetAsync(degi, 0, 800000, stream);

    cast_x_kernel<<<(N_NODES * 24) / 256, 256, 0, stream>>>(x, (half8*)xh);
    prep_bfrag_kernel<<<48, 256, 0, stream>>>(w1_l, w1_r, bfrag);

    hist_kernel<<<(N_EDGES + 255) / 256, 256, 0, stream>>>(ei, degi);
    block_sum_kernel<<<NB, 256, 0, stream>>>(degi, bsum);
    scan_bsum_kernel<<<1, 1024, 0, stream>>>(bsum, boff, row_start);
    scan_emit_kernel<<<NB, 256, 0, stream>>>(degi, boff, row_start, cursor, invdeg);
    scatter_edges_kernel<<<(N_EDGES + 255) / 256, 256, 0, stream>>>(ei, cursor, csr);

    gather_agg_kernel<<<(N_NODES * 24) / 256, 256, 0, stream>>>(
        (const half8*)xh, row_start, csr, (half8*)aggh);

    gemm_fused_kernel<<<N_NODES / 64, 512, 0, stream>>>(
        xh, aggh, invdeg, bfrag, b1, w2_l, w2_r, tl, tr);

    gather_out_kernel<<<(2 * N_EDGES + 255) / 256, 256, 0, stream>>>(
        row_start, csr, tl, tr, invdeg, b2, ei, out);
}